// Round 6
// baseline (203.369 us; speedup 1.0000x reference)
//
#include <hip/hip_runtime.h>
#include <hip/hip_bf16.h>

typedef __bf16 bf16_t;
typedef __bf16 bf16x8 __attribute__((ext_vector_type(8)));
typedef __bf16 bf16x4 __attribute__((ext_vector_type(4)));
typedef float f32x4 __attribute__((ext_vector_type(4)));
typedef float f32x16 __attribute__((ext_vector_type(16)));

#define NB 2
#define SEQ 2048
#define DMODEL 1024
#define NHEAD 16
#define DHEAD 64

__device__ inline void gload_lds16(const void* g, void* lds) {
  __builtin_amdgcn_global_load_lds((const __attribute__((address_space(1))) void*)g,
                                   (__attribute__((address_space(3))) void*)lds,
                                   16, 0, 0);
}

// ---------------- fused fp32 -> bf16 convert (H + 4 weights, one launch) ----------------
__global__ __launch_bounds__(256) void cvt_all_kernel(
    const float* __restrict__ H,  const float* __restrict__ Wq, const float* __restrict__ Wk,
    const float* __restrict__ Wv, const float* __restrict__ Wo,
    bf16_t* __restrict__ Hb, bf16_t* __restrict__ Wqb, bf16_t* __restrict__ Wkb,
    bf16_t* __restrict__ Wvb, bf16_t* __restrict__ Wob)
{
  const int b = blockIdx.x;
  const float* src; bf16_t* dst; int idx;
  if (b < 4096) { src = H; dst = Hb; idx = b; }
  else {
    const int r = b - 4096; const int s = r >> 10; idx = r & 1023;
    src = (s == 0) ? Wq : (s == 1) ? Wk : (s == 2) ? Wv : Wo;
    dst = (s == 0) ? Wqb : (s == 1) ? Wkb : (s == 2) ? Wvb : Wob;
  }
  const int i = idx * 256 + threadIdx.x;
  float4 v = ((const float4*)src)[i];
  bf16x4 o;
  o[0] = (bf16_t)v.x; o[1] = (bf16_t)v.y; o[2] = (bf16_t)v.z; o[3] = (bf16_t)v.w;
  ((bf16x4*)dst)[i] = o;
}

// ---------------- bf16 TN GEMM: C[M][N] = A[M][K] * W[N][K]^T + bias ----------------
// 128x128 tile, BK=64 (XOR-swizzled LDS), 4 waves (2x2), 16x16x32 MFMA.
// MODE 0: plain fp32 out. MODE 1: per-head normalize; z=0/1 -> bf16 Q/K; z=2 -> bf16 V^T.
template<int MODE>
__global__ __launch_bounds__(256) void gemm_bt_kernel(
    const bf16_t* __restrict__ A,
    const bf16_t* __restrict__ W0, const bf16_t* __restrict__ W1, const bf16_t* __restrict__ W2,
    const float* __restrict__ bias0, const float* __restrict__ bias1, const float* __restrict__ bias2,
    void* out0, void* out1, void* out2)
{
  __shared__ bf16_t As[128 * 64];   // [row][64 bf16 = 128B], XOR-swizzled
  __shared__ bf16_t Bs[128 * 64];
  const int tid = threadIdx.x;
  const int lane = tid & 63;
  const int w = tid >> 6;
  const int mt = blockIdx.y, nt = blockIdx.x, z = blockIdx.z;
  const bf16_t* Wp = (z == 0) ? W0 : ((z == 1) ? W1 : W2);
  const float* bp  = (z == 0) ? bias0 : ((z == 1) ? bias1 : bias2);

  const int wr = w >> 1, wc = w & 1;
  const int fr = lane & 15, fq = lane >> 4;

  // staging: wave w owns chunks 4w..4w+3 (chunk = 8 rows x 128B = 1KB)
  const int r_in = lane >> 3;                            // row within chunk
  const int cswz = ((lane & 7) ^ (r_in & 7)) << 4;       // pre-swizzled source col byte
  const unsigned lbase = (unsigned)__builtin_amdgcn_readfirstlane(w * 4096);

  f32x4 acc[4][4] = {};

  const char* Ab = (const char*)(A + (size_t)mt * 128 * DMODEL);
  const char* Bb = (const char*)(Wp + (size_t)nt * 128 * DMODEL);

  for (int kt = 0; kt < DMODEL / 64; ++kt) {
    const size_t k0b = (size_t)kt * 128;                 // 64 bf16 = 128B
    #pragma unroll
    for (int i = 0; i < 4; ++i) {
      const size_t row = (size_t)(w * 32 + i * 8 + r_in);
      gload_lds16(Ab + row * (DMODEL * 2) + k0b + cswz, (char*)As + lbase + i * 1024);
      gload_lds16(Bb + row * (DMODEL * 2) + k0b + cswz, (char*)Bs + lbase + i * 1024);
    }
    __syncthreads();

    bf16x8 a[4][2], b[4][2];
    #pragma unroll
    for (int m = 0; m < 4; ++m)
      #pragma unroll
      for (int ks = 0; ks < 2; ++ks)
        a[m][ks] = *(const bf16x8*)((const char*)As + (wr * 64 + m * 16 + fr) * 128 +
                                    ((ks * 64 + fq * 16) ^ ((fr & 7) << 4)));
    #pragma unroll
    for (int n = 0; n < 4; ++n)
      #pragma unroll
      for (int ks = 0; ks < 2; ++ks)
        b[n][ks] = *(const bf16x8*)((const char*)Bs + (wc * 64 + n * 16 + fr) * 128 +
                                    ((ks * 64 + fq * 16) ^ ((fr & 7) << 4)));
    __builtin_amdgcn_s_setprio(1);
    #pragma unroll
    for (int m = 0; m < 4; ++m)
      #pragma unroll
      for (int n = 0; n < 4; ++n)
        #pragma unroll
        for (int ks = 0; ks < 2; ++ks)
          acc[m][n] = __builtin_amdgcn_mfma_f32_16x16x32_bf16(a[m][ks], b[n][ks], acc[m][n], 0, 0, 0);
    __builtin_amdgcn_s_setprio(0);
    __syncthreads();
  }

  float bv[4];
  const int cb = nt * 128 + wc * 64;
  #pragma unroll
  for (int n = 0; n < 4; ++n) bv[n] = bp[cb + n * 16 + fr];

  if constexpr (MODE == 0) {
    float* outp = (float*)out0;
    #pragma unroll
    for (int m = 0; m < 4; ++m) {
      #pragma unroll
      for (int j = 0; j < 4; ++j) {
        const int row = mt * 128 + wr * 64 + m * 16 + fq * 4 + j;
        float* orow = outp + (size_t)row * DMODEL + cb;
        #pragma unroll
        for (int n = 0; n < 4; ++n)
          orow[n * 16 + fr] = acc[m][n][j] + bv[n];
      }
    }
  } else {
    const int h = nt * 2 + wc;  // head index
    #pragma unroll
    for (int m = 0; m < 4; ++m) {
      #pragma unroll
      for (int j = 0; j < 4; ++j) {
        float v0 = acc[m][0][j] + bv[0];
        float v1 = acc[m][1][j] + bv[1];
        float v2 = acc[m][2][j] + bv[2];
        float v3 = acc[m][3][j] + bv[3];
        float ss = v0 * v0 + v1 * v1 + v2 * v2 + v3 * v3;
        ss += __shfl_xor(ss, 1);
        ss += __shfl_xor(ss, 2);
        ss += __shfl_xor(ss, 4);
        ss += __shfl_xor(ss, 8);
        const float inv = 1.0f / fmaxf(sqrtf(ss), 1e-10f);
        const int row = mt * 128 + wr * 64 + m * 16 + fq * 4 + j;
        const int bb = row >> 11, sr = row & (SEQ - 1);
        if (z < 2) {
          bf16_t* op = ((z == 0) ? (bf16_t*)out0 : (bf16_t*)out1)
                       + (((size_t)(bb * NHEAD + h)) * SEQ + sr) * DHEAD;
          op[0 * 16 + fr] = (bf16_t)(v0 * inv);
          op[1 * 16 + fr] = (bf16_t)(v1 * inv);
          op[2 * 16 + fr] = (bf16_t)(v2 * inv);
          op[3 * 16 + fr] = (bf16_t)(v3 * inv);
        } else {
          bf16_t* vp = (bf16_t*)out2 + ((size_t)(bb * NHEAD + h)) * DHEAD * SEQ + sr;
          vp[(size_t)(0 * 16 + fr) * SEQ] = (bf16_t)(v0 * inv);
          vp[(size_t)(1 * 16 + fr) * SEQ] = (bf16_t)(v1 * inv);
          vp[(size_t)(2 * 16 + fr) * SEQ] = (bf16_t)(v2 * inv);
          vp[(size_t)(3 * 16 + fr) * SEQ] = (bf16_t)(v3 * inv);
        }
      }
    }
  }
}

// ---------------- MFMA spherical flash attention: 32x32x16, LDS-free ----------------
// Wave owns 32 q-rows. Swapped QK^T: S[key][q] with q = lane&31 (C-layout col).
// P -> bf16 PV B-operand via 8 v_cvt_pk_bf16_f32 + 4 v_permlane32_swap_b32 per 32 keys.
// PV computed transposed: O^T[dh][q] = V^T-frag x P-frag. l via ones-A mfma.
// K/V^T fragments are 16B-contiguous in global -> direct loads, no LDS, no vmcnt drains.
#define PSWAP(x, y) asm("v_permlane32_swap_b32 %0, %1" : "+v"(x), "+v"(y))
#define CVTPK(d, a, b) asm("v_cvt_pk_bf16_f32 %0, %1, %2" : "=v"(d) : "v"(a), "v"(b))

__global__ __launch_bounds__(256, 2) void mfma_attn_kernel(
    const bf16_t* __restrict__ Qb, const bf16_t* __restrict__ Kb,
    const bf16_t* __restrict__ Vt, bf16_t* __restrict__ Oat)
{
  // XCD-aware block map: consecutive blockIdx round-robin XCDs; give XCD x heads 4x..4x+3
  // so each XCD's L2 working set is 4 heads x 512KB = 2MB.
  const int p = blockIdx.x;            // 0..511
  const int xcd = p & 7;
  const int j = p >> 3;                // 0..63
  const int bh = xcd * 4 + (j >> 4);   // 4 heads per XCD
  const int qt = j & 15;               // 16 q-tiles (128 rows) per bh

  const int lane = threadIdx.x & 63;
  const int w = threadIdx.x >> 6;
  const int l31 = lane & 31, l5 = lane >> 5;
  const int q0 = qt * 128 + w * 32;    // this wave's q base

  // Q B-fragments (persistent): b_q[m] = Q[q0+l31][m*16 + l5*8 .. +7]
  const bf16_t* Qp = Qb + ((size_t)bh * SEQ + q0 + l31) * DHEAD + l5 * 8;
  bf16x8 b_q[4];
  #pragma unroll
  for (int m = 0; m < 4; ++m)
    b_q[m] = *(const bf16x8*)(Qp + m * 16);

  bf16x8 a_one;
  #pragma unroll
  for (int i = 0; i < 8; ++i) a_one[i] = (bf16_t)1.0f;

  const bf16_t* Kp = Kb + (size_t)bh * SEQ * DHEAD + l31 * DHEAD + l5 * 8;  // +key*64
  const bf16_t* Vp = Vt + (size_t)bh * DHEAD * SEQ + (size_t)l31 * SEQ + l5 * 8;  // +dh*2048+key

  f32x16 acc_o0 = {}, acc_o1 = {}, acc_l = {};

  #pragma unroll 2
  for (int kb = 0; kb < SEQ / 32; ++kb) {
    __builtin_amdgcn_s_barrier();      // keep the block's 4 waves L1-coherent (no LDS deps)

    // K A-frags: a_k[m] = K[kb*32 + l31][m*16 + l5*8 ..+7]
    const bf16_t* kp = Kp + (size_t)kb * 32 * DHEAD;
    bf16x8 a_k0 = *(const bf16x8*)(kp);
    bf16x8 a_k1 = *(const bf16x8*)(kp + 16);
    bf16x8 a_k2 = *(const bf16x8*)(kp + 32);
    bf16x8 a_k3 = *(const bf16x8*)(kp + 48);
    // V^T A-frags: a_v[blk][ks] = Vt[blk*32 + l31][kb*32 + ks*16 + l5*8 ..+7]
    const bf16_t* vp = Vp + kb * 32;
    bf16x8 a_v00 = *(const bf16x8*)(vp);
    bf16x8 a_v01 = *(const bf16x8*)(vp + 16);
    bf16x8 a_v10 = *(const bf16x8*)(vp + (size_t)32 * SEQ);
    bf16x8 a_v11 = *(const bf16x8*)(vp + (size_t)32 * SEQ + 16);

    // ---- QK^T (swapped): S[key=crow(r,l5)+kb*32][q=l31] ----
    f32x16 accp = {};
    __builtin_amdgcn_s_setprio(1);
    accp = __builtin_amdgcn_mfma_f32_32x32x16_bf16(a_k0, b_q[0], accp, 0, 0, 0);
    accp = __builtin_amdgcn_mfma_f32_32x32x16_bf16(a_k1, b_q[1], accp, 0, 0, 0);
    accp = __builtin_amdgcn_mfma_f32_32x32x16_bf16(a_k2, b_q[2], accp, 0, 0, 0);
    accp = __builtin_amdgcn_mfma_f32_32x32x16_bf16(a_k3, b_q[3], accp, 0, 0, 0);
    __builtin_amdgcn_s_setprio(0);

    // ---- score transform: w = exp(asin(c)/8)  (scale-invariant form; pure FMA) ----
    float pv[16];
    #pragma unroll
    for (int r = 0; r < 16; ++r) {
      const float cval = accp[r];
      const float c2 = cval * cval;
      float a = fmaf(c2, 0.00379774f, 0.00558036f);
      a = fmaf(c2, a, 0.00937500f);
      a = fmaf(c2, a, 0.02083333f);
      a = fmaf(c2, a, 0.12500000f);
      const float s = a * cval;          // asin(c)/8
      float e = fmaf(s, 0.16666667f, 0.5f);
      e = fmaf(s, e, 1.0f);
      e = fmaf(s, e, 1.0f);              // exp(s), deg-3
      pv[r] = e;
    }

    // ---- P -> bf16 PV B-fragments (half-wave exchange) ----
    unsigned dwA0, dwA1, dwA2, dwA3, dwB0, dwB1, dwB2, dwB3;
    CVTPK(dwA0, pv[0], pv[1]);  CVTPK(dwB0, pv[2], pv[3]);
    CVTPK(dwA1, pv[4], pv[5]);  CVTPK(dwB1, pv[6], pv[7]);
    CVTPK(dwA2, pv[8], pv[9]);  CVTPK(dwB2, pv[10], pv[11]);
    CVTPK(dwA3, pv[12], pv[13]); CVTPK(dwB3, pv[14], pv[15]);
    PSWAP(dwA0, dwA1);  PSWAP(dwB0, dwB1);   // -> slots for keys kb*32 + 0..15
    PSWAP(dwA2, dwA3);  PSWAP(dwB2, dwB3);   // -> slots for keys kb*32 + 16..31
    typedef unsigned u32x4 __attribute__((ext_vector_type(4)));
    u32x4 t0 = { dwA0, dwB0, dwA1, dwB1 };
    u32x4 t1 = { dwA2, dwB2, dwA3, dwB3 };
    bf16x8 pf0 = __builtin_bit_cast(bf16x8, t0);
    bf16x8 pf1 = __builtin_bit_cast(bf16x8, t1);

    // ---- PV (transposed) + l ----
    __builtin_amdgcn_s_setprio(1);
    acc_o0 = __builtin_amdgcn_mfma_f32_32x32x16_bf16(a_v00, pf0, acc_o0, 0, 0, 0);
    acc_o0 = __builtin_amdgcn_mfma_f32_32x32x16_bf16(a_v01, pf1, acc_o0, 0, 0, 0);
    acc_o1 = __builtin_amdgcn_mfma_f32_32x32x16_bf16(a_v10, pf0, acc_o1, 0, 0, 0);
    acc_o1 = __builtin_amdgcn_mfma_f32_32x32x16_bf16(a_v11, pf1, acc_o1, 0, 0, 0);
    acc_l  = __builtin_amdgcn_mfma_f32_32x32x16_bf16(a_one, pf0, acc_l, 0, 0, 0);
    acc_l  = __builtin_amdgcn_mfma_f32_32x32x16_bf16(a_one, pf1, acc_l, 0, 0, 0);
    __builtin_amdgcn_s_setprio(0);
  }

  // ---- epilogue: one rcp per lane (all outputs share q = l31) ----
  const float invl = __builtin_amdgcn_rcpf(acc_l[0]);
  const int bb = bh >> 4, h = bh & 15;
  bf16_t* op = Oat + ((size_t)bb * SEQ + q0 + l31) * DMODEL + h * DHEAD;
  #pragma unroll
  for (int blk = 0; blk < 2; ++blk) {
    const f32x16& ao = blk ? acc_o1 : acc_o0;
    #pragma unroll
    for (int g = 0; g < 4; ++g) {
      bf16x4 ov;
      ov[0] = (bf16_t)(ao[4 * g + 0] * invl);
      ov[1] = (bf16_t)(ao[4 * g + 1] * invl);
      ov[2] = (bf16_t)(ao[4 * g + 2] * invl);
      ov[3] = (bf16_t)(ao[4 * g + 3] * invl);
      const int dh0 = blk * 32 + 8 * g + 4 * l5;
      *(bf16x4*)(op + dh0) = ov;
    }
  }
}

extern "C" void kernel_launch(void* const* d_in, const int* in_sizes, int n_in,
                              void* d_out, int out_size, void* d_ws, size_t ws_size,
                              hipStream_t stream)
{
  const float* H  = (const float*)d_in[0];
  const float* Wq = (const float*)d_in[1];
  const float* bq = (const float*)d_in[2];
  const float* Wk = (const float*)d_in[3];
  const float* bk = (const float*)d_in[4];
  const float* Wv = (const float*)d_in[5];
  const float* bv = (const float*)d_in[6];
  const float* Wo = (const float*)d_in[7];
  const float* bo = (const float*)d_in[8];
  float* out = (float*)d_out;

  char* ws = (char*)d_ws;
  bf16_t* Hb  = (bf16_t*)(ws);                    // 8 MB  [B*S][1024]
  bf16_t* Wqb = (bf16_t*)(ws + (8u << 20));       // 2 MB each
  bf16_t* Wkb = (bf16_t*)(ws + (10u << 20));
  bf16_t* Wvb = (bf16_t*)(ws + (12u << 20));
  bf16_t* Wob = (bf16_t*)(ws + (14u << 20));
  bf16_t* Qbf = (bf16_t*)(ws + (16u << 20));      // 8 MB  [BH][S][64]
  bf16_t* Kbf = (bf16_t*)(ws + (24u << 20));      // 8 MB  [BH][S][64]
  bf16_t* Vtb = (bf16_t*)(ws + (32u << 20));      // 8 MB  [BH][64][S]
  bf16_t* Oat = (bf16_t*)(ws + (40u << 20));      // 8 MB  [B][S][1024]

  // fp32 -> bf16 converts (single launch)
  cvt_all_kernel<<<8192, 256, 0, stream>>>(H, Wq, Wk, Wv, Wo, Hb, Wqb, Wkb, Wvb, Wob);

  // Q/K/V projections + bias + per-head normalize -> bf16 Q,K,[V^T]
  gemm_bt_kernel<1><<<dim3(8, 32, 3), 256, 0, stream>>>(
      Hb, Wqb, Wkb, Wvb, bq, bk, bv, Qbf, Kbf, Vtb);

  // MFMA spherical flash attention (LDS-free, 32x32x16)
  mfma_attn_kernel<<<512, 256, 0, stream>>>(Qbf, Kbf, Vtb, Oat);

  // output projection -> d_out fp32 [B][S][1024]
  gemm_bt_kernel<0><<<dim3(8, 32, 1), 256, 0, stream>>>(
      Oat, Wob, Wob, Wob, bo, bo, bo, out, out, out);
}